// Round 13
// baseline (1201.878 us; speedup 1.0000x reference)
//
#include <hip/hip_runtime.h>
#include <hip/hip_fp16.h>
#include <cmath>

// ---------------------------------------------------------------------------
// DragonHGT R13: head-pair-split edge kernels (2x waves, 16B/lane gathers,
// 2x unrolled) + consolidated dispatches + fp16 MFMA GEMMs (BK=64, XOR LDS
// via pre-swizzled global_load_lds). CSR edge pipeline.
// N=50000 x 2 node types, E=200000 x 3 relations, C=256 (H=4, D=64).
// ---------------------------------------------------------------------------

#define CDIM 256
#define AR_R (256 * 256)

using f16x8 = __attribute__((ext_vector_type(8))) _Float16;
using f16x4 = __attribute__((ext_vector_type(4))) _Float16;
using f16x2 = __attribute__((ext_vector_type(2))) _Float16;
using f32x4 = __attribute__((ext_vector_type(4))) float;

__device__ __forceinline__ float gelu_f(float x) {
    return 0.5f * x * (1.0f + erff(x * 0.70710678118654752f));
}

__device__ __forceinline__ float dot8f(const f16x8 a, const f16x8 b, float r) {
#if __has_builtin(__builtin_amdgcn_fdot2)
#pragma unroll
    for (int t = 0; t < 4; ++t) {
        f16x2 av = {a[2 * t], a[2 * t + 1]};
        f16x2 bv = {b[2 * t], b[2 * t + 1]};
        r = __builtin_amdgcn_fdot2(av, bv, r, false);
    }
#else
#pragma unroll
    for (int t = 0; t < 8; ++t) r += (float)a[t] * (float)b[t];
#endif
    return r;
}

__global__ __launch_bounds__(256) void zero_k(int* __restrict__ p, size_t n) {
    size_t i = (size_t)blockIdx.x * blockDim.x + threadIdx.x;
    const size_t stride = (size_t)gridDim.x * blockDim.x;
    for (; i < n; i += stride) p[i] = 0;
}

__global__ __launch_bounds__(256) void cvt2_k(const float* __restrict__ xe_in,
                                              const float* __restrict__ xs_in,
                                              _Float16* __restrict__ xeH,
                                              _Float16* __restrict__ xsH,
                                              size_t n4) {
    const float* in = blockIdx.y ? xs_in : xe_in;
    _Float16* out = blockIdx.y ? xsH : xeH;
    size_t i = (size_t)blockIdx.x * blockDim.x + threadIdx.x;
    const size_t stride = (size_t)gridDim.x * blockDim.x;
    for (; i < n4; i += stride) {
        const float4 v = ((const float4*)in)[i];
        f16x4 o;
        o[0] = (_Float16)v.x; o[1] = (_Float16)v.y;
        o[2] = (_Float16)v.z; o[3] = (_Float16)v.w;
        ((f16x4*)out)[i] = o;
    }
}

// ---------------------------------------------------------------------------
// Weight prep (single dispatch for all 3 layers).
// ---------------------------------------------------------------------------
__device__ __forceinline__ void cvtT_dev(const float* __restrict__ W,
                                         _Float16* __restrict__ dst) {
    const int o = blockIdx.x, c = threadIdx.x;
    dst[(size_t)o * 256 + c] = (_Float16)W[(size_t)c * 256 + o];
}

__device__ __forceinline__ void foldT_dev(const float* __restrict__ Wbase,
                                          const float* __restrict__ T,
                                          _Float16* __restrict__ dst) {
    __shared__ float row[256];
    const int c = blockIdx.x, t = threadIdx.x;
    row[t] = Wbase[(size_t)c * 256 + t];
    __syncthreads();
    const int h = t >> 6, f = t & 63;
    const float* Th = T + h * 4096;
    float acc = 0.f;
#pragma unroll 8
    for (int d = 0; d < 64; ++d) acc += row[h * 64 + d] * Th[d * 64 + f];
    dst[(size_t)t * 256 + c] = (_Float16)acc;
}

// arena per layer: [0]q_e [1]kA0 [2]kA1 [3]q_s [4]kA2 [5]vM0 [6]vM1 [7]vM2
//                  [8]WaT0 [9]WaT1
__global__ __launch_bounds__(256) void prep_layer_k(
    const float* __restrict__ Wk, const float* __restrict__ Wq,
    const float* __restrict__ Wv, const float* __restrict__ Wa,
    const float* __restrict__ Arel, const float* __restrict__ Mrel,
    _Float16* __restrict__ arena) {
    const size_t CC = 65536, HDD = 16384;
    const int l = blockIdx.y / 10;
    const int c = blockIdx.y % 10;
    _Float16* L = arena + (size_t)l * 10 * AR_R;
    const float* Wk0 = Wk + (l * 2 + 0) * CC;
    const float* Wk1 = Wk + (l * 2 + 1) * CC;
    const float* Wv0 = Wv + (l * 2 + 0) * CC;
    const float* Wv1 = Wv + (l * 2 + 1) * CC;
    switch (c) {
        case 0: cvtT_dev(Wq + (l * 2 + 0) * CC, L); break;
        case 1: foldT_dev(Wk0, Arel + (l * 3 + 0) * HDD, L + 1 * AR_R); break;
        case 2: foldT_dev(Wk0, Arel + (l * 3 + 1) * HDD, L + 2 * AR_R); break;
        case 3: cvtT_dev(Wq + (l * 2 + 1) * CC, L + 3 * AR_R); break;
        case 4: foldT_dev(Wk1, Arel + (l * 3 + 2) * HDD, L + 4 * AR_R); break;
        case 5: foldT_dev(Wv0, Mrel + (l * 3 + 0) * HDD, L + 5 * AR_R); break;
        case 6: foldT_dev(Wv0, Mrel + (l * 3 + 1) * HDD, L + 6 * AR_R); break;
        case 7: foldT_dev(Wv1, Mrel + (l * 3 + 2) * HDD, L + 7 * AR_R); break;
        case 8: cvtT_dev(Wa + (l * 2 + 0) * CC, L + 8 * AR_R); break;
        case 9: cvtT_dev(Wa + (l * 2 + 1) * CC, L + 9 * AR_R); break;
    }
}

__global__ __launch_bounds__(256) void prep_stack_k(const float* __restrict__ Wsh,
                                                    _Float16* __restrict__ SA) {
    cvtT_dev(Wsh + (size_t)blockIdx.y * 65536, SA + (size_t)blockIdx.y * AR_R);
}

__global__ __launch_bounds__(256) void prep_heads_k(const float* __restrict__ Wt1,
                                                    _Float16* __restrict__ HA) {
    const int o = blockIdx.x, k = blockIdx.y, c = threadIdx.x;
    HA[(size_t)(k * 128 + o) * 256 + c] =
        (_Float16)Wt1[(size_t)k * 256 * 128 + (size_t)c * 128 + o];
}

// ---------------------------------------------------------------------------
// fp16 MFMA GEMM body (BK=64; global_load_lds width=16, pre-swizzled source).
// ---------------------------------------------------------------------------
template <int EPI, bool SPLIT>
__device__ __forceinline__ void gemm_body(
    const _Float16* __restrict__ A, const _Float16* __restrict__ Bt,
    _Float16* __restrict__ C, int M, int Nc, int bm, int bn, size_t bufStride,
    const float* __restrict__ bias, const float* __restrict__ skipv,
    _Float16* As, _Float16* Bs) {
    const int tid = threadIdx.x;
    const int wave = tid >> 6, lane = tid & 63;
    const int wm = (wave >> 1) * 64, wn = (wave & 1) * 64;
    const int l15 = lane & 15, g = lane >> 4;

    f32x4 acc[4][4] = {};

    for (int k0 = 0; k0 < 256; k0 += 64) {
        __syncthreads();
#pragma unroll
        for (int p = 0; p < 4; ++p) {
            const int slot = p * 256 + tid;
            const int r = slot >> 3;
            const int cb = ((slot & 7) << 4) ^ ((r & 7) << 4);
            int gr = bm + r; if (gr >= M) gr = M - 1;
            __builtin_amdgcn_global_load_lds(
                (const __attribute__((address_space(1))) void*)
                    ((const char*)A + ((size_t)gr * 256 + k0) * 2 + cb),
                (__attribute__((address_space(3))) void*)((char*)As + slot * 16),
                16, 0, 0);
            __builtin_amdgcn_global_load_lds(
                (const __attribute__((address_space(1))) void*)
                    ((const char*)Bt + ((size_t)(bn + r) * 256 + k0) * 2 + cb),
                (__attribute__((address_space(3))) void*)((char*)Bs + slot * 16),
                16, 0, 0);
        }
        __syncthreads();
#pragma unroll
        for (int sub = 0; sub < 2; ++sub) {
            f16x8 af[4], bf[4];
#pragma unroll
            for (int i = 0; i < 4; ++i) {
                const int ra = wm + i * 16 + l15;
                const int rb = wn + i * 16 + l15;
                const int ka = (sub * 64 + g * 16) ^ ((ra & 7) << 4);
                const int kb = (sub * 64 + g * 16) ^ ((rb & 7) << 4);
                af[i] = *(const f16x8*)((const char*)As + ra * 128 + ka);
                bf[i] = *(const f16x8*)((const char*)Bs + rb * 128 + kb);
            }
#pragma unroll
            for (int mi = 0; mi < 4; ++mi)
#pragma unroll
                for (int ni = 0; ni < 4; ++ni)
                    acc[mi][ni] = __builtin_amdgcn_mfma_f32_16x16x32_f16(
                        af[mi], bf[ni], acc[mi][ni], 0, 0, 0);
        }
    }

    float be = 0.f, ombe = 0.f;
    if (EPI == 1) {
        const float s = skipv[0];
        be = 1.0f / (1.0f + expf(-s));
        ombe = 1.0f - be;
    }
#pragma unroll
    for (int mi = 0; mi < 4; ++mi) {
#pragma unroll
        for (int r = 0; r < 4; ++r) {
            const int row = bm + wm + mi * 16 + g * 4 + r;
            if (row >= M) continue;
#pragma unroll
            for (int ni = 0; ni < 4; ++ni) {
                const int colg = bn + wn + ni * 16 + l15;
                float v = acc[mi][ni][r];
                size_t idx;
                if (SPLIT)
                    idx = (size_t)(colg >> 8) * bufStride + (size_t)row * 256 +
                          (colg & 255);
                else
                    idx = (size_t)row * Nc + colg;
                if (EPI == 1) v = be * v + ombe * (float)C[idx];
                if (EPI == 2) v = fmaxf(v + bias[colg], 0.f);
                C[idx] = (_Float16)v;
            }
        }
    }
}

template <int EPI, bool SPLIT>
__global__ __launch_bounds__(256) void gemm_h(
    const _Float16* __restrict__ A, const _Float16* __restrict__ Bt,
    _Float16* __restrict__ C, int M, int Nc, size_t bufStride,
    const float* __restrict__ bias, const float* __restrict__ skipv) {
    __shared__ _Float16 As[128 * 64];
    __shared__ _Float16 Bs[128 * 64];
    gemm_body<EPI, SPLIT>(A, Bt, C, M, Nc, blockIdx.y * 128, blockIdx.x * 128,
                          bufStride, bias, skipv, As, Bs);
}

// Q/K projection super-dispatch: 5 jobs x 2 col-panels, grid (10, gx).
__global__ __launch_bounds__(256) void projq_k(
    const _Float16* __restrict__ xeH, const _Float16* __restrict__ xsH,
    const _Float16* __restrict__ L, _Float16* __restrict__ Hb, int M) {
    __shared__ _Float16 As[128 * 64];
    __shared__ _Float16 Bs[128 * 64];
    const int job = blockIdx.x >> 1;
    const int bn = (blockIdx.x & 1) * 128;
    const _Float16* A = (job < 3) ? xeH : xsH;
    const _Float16* Bt = L + (size_t)job * AR_R;
    _Float16* C = Hb + (size_t)job * (size_t)M * 256;
    gemm_body<0, false>(A, Bt, C, M, 256, blockIdx.y * 128, bn, 0, nullptr,
                        nullptr, As, Bs);
}

// V projection super-dispatch: 3 jobs, grid (6, gx).
__global__ __launch_bounds__(256) void projv_k(
    const _Float16* __restrict__ xeH, const _Float16* __restrict__ xsH,
    const _Float16* __restrict__ L, _Float16* __restrict__ Hb, int M) {
    __shared__ _Float16 As[128 * 64];
    __shared__ _Float16 Bs[128 * 64];
    const int job = blockIdx.x >> 1;
    const int bn = (blockIdx.x & 1) * 128;
    const _Float16* A = (job < 2) ? xeH : xsH;
    const _Float16* Bt = L + (size_t)(5 + job) * AR_R;
    const int dsti = (job == 0) ? 1 : (job == 1) ? 2 : 4;
    _Float16* C = Hb + (size_t)dsti * (size_t)M * 256;
    gemm_body<0, false>(A, Bt, C, M, 256, blockIdx.y * 128, bn, 0, nullptr,
                        nullptr, As, Bs);
}

// Fused skip-updates; grid = (4, row_panels).
__global__ __launch_bounds__(256) void update2_k(
    const _Float16* __restrict__ aggE, const _Float16* __restrict__ aggS,
    const _Float16* __restrict__ WaT0, const _Float16* __restrict__ WaT1,
    _Float16* __restrict__ xeH, _Float16* __restrict__ xsH,
    const float* __restrict__ skipb, int M) {
    __shared__ _Float16 As[128 * 64];
    __shared__ _Float16 Bs[128 * 64];
    const int sel = blockIdx.x >> 1;
    const int bn = (blockIdx.x & 1) * 128;
    const int bm = blockIdx.y * 128;
    if (sel == 0)
        gemm_body<1, false>(aggE, WaT0, xeH, M, 256, bm, bn, 0, nullptr, skipb,
                            As, Bs);
    else
        gemm_body<1, false>(aggS, WaT1, xsH, M, 256, bm, bn, 0, nullptr,
                            skipb + 1, As, Bs);
}

// ---------------------------------------------------------------------------
// CSR build: hist -> 3-phase parallel scan -> scatter (colsrc).
// ---------------------------------------------------------------------------
__global__ __launch_bounds__(256) void hist3_k(const int* __restrict__ d0,
                                               const int* __restrict__ d1,
                                               const int* __restrict__ d2,
                                               int* __restrict__ cnt, int N,
                                               int E) {
    const int i = blockIdx.x * 256 + threadIdx.x;
    if (i >= E) return;
    const int r = blockIdx.y;
    const int* d = r == 0 ? d0 : r == 1 ? d1 : d2;
    atomicAdd(&cnt[(size_t)r * N + d[i]], 1);
}

__global__ __launch_bounds__(256) void partial_k(const int* __restrict__ cnt,
                                                 int* __restrict__ partials,
                                                 int N, int PB) {
    const int r = blockIdx.y, b = blockIdx.x, tid = threadIdx.x;
    const int gi = b * 256 + tid;
    int v = (gi < N) ? cnt[(size_t)r * N + gi] : 0;
#pragma unroll
    for (int o = 1; o < 64; o <<= 1) v += __shfl_xor(v, o);
    __shared__ int ws[4];
    if ((tid & 63) == 0) ws[tid >> 6] = v;
    __syncthreads();
    if (tid == 0) partials[r * PB + b] = ws[0] + ws[1] + ws[2] + ws[3];
}

__global__ __launch_bounds__(256) void scanp_k(int* __restrict__ partials,
                                               int* __restrict__ rp, int N,
                                               int PB, int E) {
    __shared__ int lds[256];
    const int r = blockIdx.y, tid = threadIdx.x;
    const int v = (tid < PB) ? partials[r * PB + tid] : 0;
    lds[tid] = v;
    __syncthreads();
    int acc = v;
    for (int off = 1; off < 256; off <<= 1) {
        const int t = (tid >= off) ? lds[tid - off] : 0;
        __syncthreads();
        acc += t;
        lds[tid] = acc;
        __syncthreads();
    }
    if (tid < PB) partials[r * PB + tid] = acc - v;
    if (tid == 0) rp[(size_t)r * (N + 1) + N] = E;
}

__global__ __launch_bounds__(256) void rpwrite_k(const int* __restrict__ cnt,
                                                 const int* __restrict__ partials,
                                                 int* __restrict__ rp, int N,
                                                 int PB) {
    __shared__ int lds[256];
    const int r = blockIdx.y, b = blockIdx.x, tid = threadIdx.x;
    const int gi = b * 256 + tid;
    const int v = (gi < N) ? cnt[(size_t)r * N + gi] : 0;
    lds[tid] = v;
    __syncthreads();
    int acc = v;
    for (int off = 1; off < 256; off <<= 1) {
        const int t = (tid >= off) ? lds[tid - off] : 0;
        __syncthreads();
        acc += t;
        lds[tid] = acc;
        __syncthreads();
    }
    if (gi < N) rp[(size_t)r * (N + 1) + gi] = partials[r * PB + b] + acc - v;
}

__global__ __launch_bounds__(256) void scatter3_k(
    const int* __restrict__ d0, const int* __restrict__ d1,
    const int* __restrict__ d2, const int* __restrict__ s0_,
    const int* __restrict__ s1_, const int* __restrict__ s2_,
    const int* __restrict__ rp, int* __restrict__ fill,
    int* __restrict__ colsrc, int N, int E) {
    const int i = blockIdx.x * 256 + threadIdx.x;
    if (i >= E) return;
    const int r = blockIdx.y;
    const int* d = r == 0 ? d0 : r == 1 ? d1 : d2;
    const int* s = r == 0 ? s0_ : r == 1 ? s1_ : s2_;
    const int dd = d[i];
    const int p = rp[(size_t)r * (N + 1) + dd] + atomicAdd(&fill[(size_t)r * N + dd], 1);
    colsrc[(size_t)r * E + p] = s[i];
}

// ---------------------------------------------------------------------------
// Scoring, head-pair split: wave per (dst node, 2 heads). 4 groups x edge;
// lane j covers 8 halfs (16B load). Dot reduce = 3 shfl within 8-lane slice.
// grid y: 0,1 = expr hp0/hp1; 2,3 = stmt hp0/hp1. 2x unrolled.
// ---------------------------------------------------------------------------
__device__ __forceinline__ void score_rel_h(
    const f16x8 qv, const _Float16* __restrict__ kA,
    const int* __restrict__ cs, int beg, int end, float scl,
    float* __restrict__ sc, int fo, int j, int grp, int h, float& m) {
    int i = beg + grp;
    for (; i + 4 < end; i += 8) {
        const int s0 = cs[i], s1 = cs[i + 4];
        const f16x8 k0 = *(const f16x8*)&kA[(size_t)s0 * 256 + fo];
        const f16x8 k1 = *(const f16x8*)&kA[(size_t)s1 * 256 + fo];
        float p0 = dot8f(qv, k0, 0.f), p1 = dot8f(qv, k1, 0.f);
        p0 += __shfl_xor(p0, 1); p1 += __shfl_xor(p1, 1);
        p0 += __shfl_xor(p0, 2); p1 += __shfl_xor(p1, 2);
        p0 += __shfl_xor(p0, 4); p1 += __shfl_xor(p1, 4);
        const float v0 = p0 * scl, v1 = p1 * scl;
        if ((j & 7) == 0) {
            sc[(size_t)i * 4 + h] = v0;
            sc[(size_t)(i + 4) * 4 + h] = v1;
        }
        m = fmaxf(m, fmaxf(v0, v1));
    }
    if (i < end) {
        const int s0 = cs[i];
        const f16x8 k0 = *(const f16x8*)&kA[(size_t)s0 * 256 + fo];
        float p0 = dot8f(qv, k0, 0.f);
        p0 += __shfl_xor(p0, 1); p0 += __shfl_xor(p0, 2); p0 += __shfl_xor(p0, 4);
        const float v0 = p0 * scl;
        if ((j & 7) == 0) sc[(size_t)i * 4 + h] = v0;
        m = fmaxf(m, v0);
    }
}

__global__ __launch_bounds__(256) void score3_k(
    const _Float16* __restrict__ qe, const _Float16* __restrict__ kA0,
    const _Float16* __restrict__ kA1, const _Float16* __restrict__ qs,
    const _Float16* __restrict__ kA2, const int* __restrict__ rp,
    const int* __restrict__ colsrc, const float* __restrict__ muL,
    float* __restrict__ sc, float* __restrict__ mx_e,
    float* __restrict__ mx_s, int N, int E) {
    const int wid = (blockIdx.x * blockDim.x + threadIdx.x) >> 6;
    if (wid >= N) return;
    const int lane = threadIdx.x & 63;
    const int grp = lane >> 4, j = lane & 15;
    const int dom = blockIdx.y >> 1, hp = blockIdx.y & 1;
    const int h = hp * 2 + (j >> 3);
    const int fo = hp * 128 + j * 8;
    const size_t E4 = (size_t)E * 4;
    float m = -1e30f;
    if (dom == 0) {
        const f16x8 qv = *(const f16x8*)&qe[(size_t)wid * 256 + fo];
        score_rel_h(qv, kA0, colsrc, rp[wid], rp[wid + 1],
                    muL[0 * 4 + h] * 0.125f, sc, fo, j, grp, h, m);
        const int* rp2 = rp + 2 * (N + 1);
        score_rel_h(qv, kA2, colsrc + 2 * (size_t)E, rp2[wid], rp2[wid + 1],
                    muL[2 * 4 + h] * 0.125f, sc + 2 * E4, fo, j, grp, h, m);
        m = fmaxf(m, __shfl_xor(m, 16));
        m = fmaxf(m, __shfl_xor(m, 32));
        if (grp == 0 && (j & 7) == 0) mx_e[(size_t)wid * 4 + h] = m;
    } else {
        const f16x8 qv = *(const f16x8*)&qs[(size_t)wid * 256 + fo];
        const int* rp1 = rp + (N + 1);
        score_rel_h(qv, kA1, colsrc + (size_t)E, rp1[wid], rp1[wid + 1],
                    muL[1 * 4 + h] * 0.125f, sc + E4, fo, j, grp, h, m);
        m = fmaxf(m, __shfl_xor(m, 16));
        m = fmaxf(m, __shfl_xor(m, 32));
        if (grp == 0 && (j & 7) == 0) mx_s[(size_t)wid * 4 + h] = m;
    }
}

// ---------------------------------------------------------------------------
// Aggregation, head-pair split (single-pass den, 2x unrolled): per wave
// 128 features of one node; 4 groups x edge; lane j covers 8 halfs.
// Cross-group combine = plain shfl adds (same global max used).
// Distributed GELU: every lane gelu's 2 elements, f16x2 coalesced store.
// ---------------------------------------------------------------------------
__device__ __forceinline__ void agg_rel_h(
    const float* __restrict__ sc, const _Float16* __restrict__ vM,
    const int* __restrict__ cs, int beg, int end, float mh, int fo, int h,
    int grp, float* accf, float& den) {
    int i = beg + grp;
    for (; i + 4 < end; i += 8) {
        const int s0 = cs[i], s1 = cs[i + 4];
        const float w0 = __expf(sc[(size_t)i * 4 + h] - mh);
        const float w1 = __expf(sc[(size_t)(i + 4) * 4 + h] - mh);
        const f16x8 v0 = *(const f16x8*)&vM[(size_t)s0 * 256 + fo];
        const f16x8 v1 = *(const f16x8*)&vM[(size_t)s1 * 256 + fo];
        den += w0 + w1;
#pragma unroll
        for (int t = 0; t < 8; ++t)
            accf[t] += w0 * (float)v0[t] + w1 * (float)v1[t];
    }
    if (i < end) {
        const int s0 = cs[i];
        const float w0 = __expf(sc[(size_t)i * 4 + h] - mh);
        const f16x8 v0 = *(const f16x8*)&vM[(size_t)s0 * 256 + fo];
        den += w0;
#pragma unroll
        for (int t = 0; t < 8; ++t) accf[t] += w0 * (float)v0[t];
    }
}

__global__ __launch_bounds__(256) void agg3_k(
    const float* __restrict__ sc, const _Float16* __restrict__ vM0,
    const _Float16* __restrict__ vM1, const _Float16* __restrict__ vM2,
    const int* __restrict__ rp, const int* __restrict__ colsrc,
    const float* __restrict__ mx_e, const float* __restrict__ mx_s,
    _Float16* __restrict__ outE, _Float16* __restrict__ outS, int N, int E) {
    const int wid = (blockIdx.x * blockDim.x + threadIdx.x) >> 6;
    if (wid >= N) return;
    const int lane = threadIdx.x & 63;
    const int grp = lane >> 4, j = lane & 15;
    const int dom = blockIdx.y >> 1, hp = blockIdx.y & 1;
    const int h = hp * 2 + (j >> 3);
    const int fo = hp * 128 + j * 8;
    const size_t E4 = (size_t)E * 4;
    float accf[8] = {};
    float den = 0.f;
    _Float16* outp;
    if (dom == 0) {
        const float mh = mx_e[(size_t)wid * 4 + h];
        const int b0 = rp[wid], e0 = rp[wid + 1];
        const int* rp2 = rp + 2 * (N + 1);
        agg_rel_h(sc, vM0, colsrc, b0, e0, mh, fo, h, grp, accf, den);
        agg_rel_h(sc + 2 * E4, vM2, colsrc + 2 * (size_t)E, rp2[wid],
                  rp2[wid + 1], mh, fo, h, grp, accf, den);
        outp = outE;
    } else {
        const float mh = mx_s[(size_t)wid * 4 + h];
        const int* rp1 = rp + (N + 1);
        agg_rel_h(sc + E4, vM1, colsrc + (size_t)E, rp1[wid], rp1[wid + 1], mh,
                  fo, h, grp, accf, den);
        outp = outS;
    }
    den += __shfl_xor(den, 16);
    den += __shfl_xor(den, 32);
#pragma unroll
    for (int t = 0; t < 8; ++t) {
        accf[t] += __shfl_xor(accf[t], 16);
        accf[t] += __shfl_xor(accf[t], 32);
    }
    const float dinv = 1.0f / (den + 1e-16f);
    f16x2 o;
    o[0] = (_Float16)gelu_f(accf[grp * 2 + 0] * dinv);
    o[1] = (_Float16)gelu_f(accf[grp * 2 + 1] * dinv);
    *(f16x2*)&outp[(size_t)wid * 256 + fo + grp * 2] = o;
}

// ---------------------------------------------------------------------------
// Batched head epilogue.
// ---------------------------------------------------------------------------
__global__ __launch_bounds__(256) void head2_k(const _Float16* __restrict__ t,
                                               const float* __restrict__ Wt2,
                                               const float* __restrict__ bt2,
                                               float* __restrict__ out, int M) {
    const int k = blockIdx.y;
    __shared__ float Ws[128 * 8];
    __shared__ float bs[8];
    const int tid = threadIdx.x;
    const float* W2 = Wt2 + (size_t)k * 1024;
    for (int i = tid; i < 1024; i += 256) Ws[i] = W2[i];
    if (tid < 8) bs[tid] = bt2[k * 8 + tid];
    __syncthreads();
    const int OFFA[7] = {0, 3, 6, 9, 14, 15, 16};
    const int DIMSA[7] = {3, 3, 3, 5, 1, 1, 8};
    const int nl = tid >> 3, o = tid & 7;
    const int n = blockIdx.x * 32 + nl;
    if (n >= M) return;
    const _Float16* tr = &t[(size_t)n * 896 + k * 128];
    float acc = bs[o];
#pragma unroll 8
    for (int d = 0; d < 128; ++d) acc += (float)tr[d] * Ws[d * 8 + o];
    if (o < DIMSA[k]) out[(size_t)n * 24 + OFFA[k] + o] = acc;
}

// ---------------------------------------------------------------------------

extern "C" void kernel_launch(void* const* d_in, const int* in_sizes, int n_in,
                              void* d_out, int out_size, void* d_ws,
                              size_t ws_size, hipStream_t stream) {
    const float* xe_in = (const float*)d_in[0];
    const float* xs_in = (const float*)d_in[1];
    const int* ee_src = (const int*)d_in[2];
    const int* ee_dst = (const int*)d_in[3];
    const int* es_src = (const int*)d_in[4];
    const int* es_dst = (const int*)d_in[5];
    const int* se_src = (const int*)d_in[6];
    const int* se_dst = (const int*)d_in[7];
    const float* Wk = (const float*)d_in[8];
    const float* Wq = (const float*)d_in[9];
    const float* Wv = (const float*)d_in[10];
    const float* Wa = (const float*)d_in[11];
    const float* skip = (const float*)d_in[12];
    const float* Arel = (const float*)d_in[13];
    const float* Mrel = (const float*)d_in[14];
    const float* mu = (const float*)d_in[15];
    const float* Wsh = (const float*)d_in[16];
    const float* bsh = (const float*)d_in[17];
    const float* Wt1 = (const float*)d_in[18];
    const float* bt1 = (const float*)d_in[19];
    const float* Wt2 = (const float*)d_in[20];
    const float* bt2 = (const float*)d_in[21];
    float* out = (float*)d_out;

    const int N = in_sizes[0] / CDIM;  // 50000
    const int E = in_sizes[2];         // 200000
    const size_t NC = (size_t)N * CDIM;
    const size_t E4 = (size_t)E * 4;
    const size_t N4 = (size_t)N * 4;
    const int PB = (N + 255) / 256;

    const size_t halfs = 7 * NC + 32 * (size_t)AR_R + 7 * 32768;
    const size_t floats = 3 * E4 + 2 * N4;
    const size_t ints =
        3 * (size_t)(N + 1) + 3 * (size_t)E + 3 * (size_t)N + 3 * (size_t)PB;
    const size_t need = halfs * 2 + floats * 4 + ints * 4;
    if (ws_size < need) return;

    _Float16* xeH = (_Float16*)d_ws;
    _Float16* xsH = xeH + NC;
    _Float16* Hb = xsH + NC;
    _Float16* H1 = Hb;
    _Float16* H2 = Hb + NC;
    _Float16* H3 = Hb + 2 * NC;
    _Float16* H4 = Hb + 3 * NC;
    _Float16* H5 = Hb + 4 * NC;
    _Float16* arena = Hb + 5 * NC;
    _Float16* SA = arena + (size_t)30 * AR_R;
    _Float16* HA = SA + (size_t)2 * AR_R;
    float* sc = (float*)(HA + (size_t)7 * 32768);
    float* mx_e = sc + 3 * E4;
    float* mx_s = mx_e + N4;
    int* rp = (int*)(mx_s + N4);
    int* colsrc = rp + 3 * (size_t)(N + 1);
    int* cnt = colsrc + 3 * (size_t)E;
    int* partials = cnt + 3 * (size_t)N;

    const int gx = (N + 127) / 128;
    const dim3 e3((E + 255) / 256, 3);
    const dim3 p3(PB, 3);
    const int wave_blocks = (N + 3) / 4;
    const int zc_blocks = (3 * N + 255) / 256;

    // ---- CSR build ----
    zero_k<<<zc_blocks, 256, 0, stream>>>(cnt, 3 * (size_t)N);
    hist3_k<<<e3, 256, 0, stream>>>(ee_dst, es_dst, se_dst, cnt, N, E);
    partial_k<<<p3, 256, 0, stream>>>(cnt, partials, N, PB);
    scanp_k<<<dim3(1, 3), 256, 0, stream>>>(partials, rp, N, PB, E);
    rpwrite_k<<<p3, 256, 0, stream>>>(cnt, partials, rp, N, PB);
    zero_k<<<zc_blocks, 256, 0, stream>>>(cnt, 3 * (size_t)N);
    scatter3_k<<<e3, 256, 0, stream>>>(ee_dst, es_dst, se_dst, ee_src, es_src,
                                       se_src, rp, cnt, colsrc, N, E);

    // ---- weight prep ----
    prep_layer_k<<<dim3(256, 30), 256, 0, stream>>>(Wk, Wq, Wv, Wa, Arel, Mrel,
                                                    arena);
    prep_stack_k<<<dim3(256, 2), 256, 0, stream>>>(Wsh, SA);
    prep_heads_k<<<dim3(128, 7), 256, 0, stream>>>(Wt1, HA);

    // ---- initial fp16 activations ----
    cvt2_k<<<dim3(1024, 2), 256, 0, stream>>>(xe_in, xs_in, xeH, xsH, NC / 4);

    for (int l = 0; l < 3; ++l) {
        _Float16* L = arena + (size_t)l * 10 * AR_R;
        projq_k<<<dim3(10, gx), 256, 0, stream>>>(xeH, xsH, L, Hb, N);
        score3_k<<<dim3(wave_blocks, 4), 256, 0, stream>>>(
            H1, H2, H3, H4, H5, rp, colsrc, mu + l * 12, sc, mx_e, mx_s, N, E);
        projv_k<<<dim3(6, gx), 256, 0, stream>>>(xeH, xsH, L, Hb, N);
        agg3_k<<<dim3(wave_blocks, 4), 256, 0, stream>>>(
            sc, H2, H3, H5, rp, colsrc, mx_e, mx_s, H1, H4, N, E);
        update2_k<<<dim3(4, gx), 256, 0, stream>>>(
            H1, H4, L + 8 * AR_R, L + 9 * AR_R, xeH, xsH, skip + l * 2, N);
    }

    // shared linear stack
    gemm_h<2, false><<<dim3(2, gx), 256, 0, stream>>>(xeH, SA, H5, N, 256, 0,
                                                      bsh, nullptr);
    gemm_h<2, false><<<dim3(2, gx), 256, 0, stream>>>(H5, SA + AR_R, xsH, N,
                                                      256, 0, bsh + 256, nullptr);
    // 7 task heads
    gemm_h<2, false><<<dim3(7, gx), 256, 0, stream>>>(xsH, HA, Hb, N, 896, 0,
                                                      bt1, nullptr);
    head2_k<<<dim3((N + 31) / 32, 7), 256, 0, stream>>>(Hb, Wt2, bt2, out, N);
}

// Round 14
// 1075.494 us; speedup vs baseline: 1.1175x; 1.1175x over previous
//
#include <hip/hip_runtime.h>
#include <hip/hip_fp16.h>
#include <cmath>

// ---------------------------------------------------------------------------
// DragonHGT R14: revert of R13's head-split regression -> R12 structure
// (consolidated dispatches, 16-lane-group edge kernels) + 2x-unrolled
// aggregation gather. fp16 MFMA GEMMs (BK=64, XOR LDS via pre-swizzled
// global_load_lds). CSR edge pipeline, parallel 3-phase scan.
// N=50000 x 2 node types, E=200000 x 3 relations, C=256 (H=4, D=64).
// ---------------------------------------------------------------------------

#define CDIM 256
#define AR_R (256 * 256)

using f16x8 = __attribute__((ext_vector_type(8))) _Float16;
using f16x4 = __attribute__((ext_vector_type(4))) _Float16;
using f16x2 = __attribute__((ext_vector_type(2))) _Float16;
using f32x4 = __attribute__((ext_vector_type(4))) float;

__device__ __forceinline__ float gelu_f(float x) {
    return 0.5f * x * (1.0f + erff(x * 0.70710678118654752f));
}

__device__ __forceinline__ float dot8f(const f16x8 a, const f16x8 b, float r) {
#if __has_builtin(__builtin_amdgcn_fdot2)
#pragma unroll
    for (int t = 0; t < 4; ++t) {
        f16x2 av = {a[2 * t], a[2 * t + 1]};
        f16x2 bv = {b[2 * t], b[2 * t + 1]};
        r = __builtin_amdgcn_fdot2(av, bv, r, false);
    }
#else
#pragma unroll
    for (int t = 0; t < 8; ++t) r += (float)a[t] * (float)b[t];
#endif
    return r;
}

__global__ __launch_bounds__(256) void zero_k(int* __restrict__ p, size_t n) {
    size_t i = (size_t)blockIdx.x * blockDim.x + threadIdx.x;
    const size_t stride = (size_t)gridDim.x * blockDim.x;
    for (; i < n; i += stride) p[i] = 0;
}

__global__ __launch_bounds__(256) void cvt2_k(const float* __restrict__ xe_in,
                                              const float* __restrict__ xs_in,
                                              _Float16* __restrict__ xeH,
                                              _Float16* __restrict__ xsH,
                                              size_t n4) {
    const float* in = blockIdx.y ? xs_in : xe_in;
    _Float16* out = blockIdx.y ? xsH : xeH;
    size_t i = (size_t)blockIdx.x * blockDim.x + threadIdx.x;
    const size_t stride = (size_t)gridDim.x * blockDim.x;
    for (; i < n4; i += stride) {
        const float4 v = ((const float4*)in)[i];
        f16x4 o;
        o[0] = (_Float16)v.x; o[1] = (_Float16)v.y;
        o[2] = (_Float16)v.z; o[3] = (_Float16)v.w;
        ((f16x4*)out)[i] = o;
    }
}

// ---------------------------------------------------------------------------
// Weight prep (single dispatch for all 3 layers).
// ---------------------------------------------------------------------------
__device__ __forceinline__ void cvtT_dev(const float* __restrict__ W,
                                         _Float16* __restrict__ dst) {
    const int o = blockIdx.x, c = threadIdx.x;
    dst[(size_t)o * 256 + c] = (_Float16)W[(size_t)c * 256 + o];
}

__device__ __forceinline__ void foldT_dev(const float* __restrict__ Wbase,
                                          const float* __restrict__ T,
                                          _Float16* __restrict__ dst) {
    __shared__ float row[256];
    const int c = blockIdx.x, t = threadIdx.x;
    row[t] = Wbase[(size_t)c * 256 + t];
    __syncthreads();
    const int h = t >> 6, f = t & 63;
    const float* Th = T + h * 4096;
    float acc = 0.f;
#pragma unroll 8
    for (int d = 0; d < 64; ++d) acc += row[h * 64 + d] * Th[d * 64 + f];
    dst[(size_t)t * 256 + c] = (_Float16)acc;
}

// arena per layer: [0]q_e [1]kA0 [2]kA1 [3]q_s [4]kA2 [5]vM0 [6]vM1 [7]vM2
//                  [8]WaT0 [9]WaT1
__global__ __launch_bounds__(256) void prep_layer_k(
    const float* __restrict__ Wk, const float* __restrict__ Wq,
    const float* __restrict__ Wv, const float* __restrict__ Wa,
    const float* __restrict__ Arel, const float* __restrict__ Mrel,
    _Float16* __restrict__ arena) {
    const size_t CC = 65536, HDD = 16384;
    const int l = blockIdx.y / 10;
    const int c = blockIdx.y % 10;
    _Float16* L = arena + (size_t)l * 10 * AR_R;
    const float* Wk0 = Wk + (l * 2 + 0) * CC;
    const float* Wk1 = Wk + (l * 2 + 1) * CC;
    const float* Wv0 = Wv + (l * 2 + 0) * CC;
    const float* Wv1 = Wv + (l * 2 + 1) * CC;
    switch (c) {
        case 0: cvtT_dev(Wq + (l * 2 + 0) * CC, L); break;
        case 1: foldT_dev(Wk0, Arel + (l * 3 + 0) * HDD, L + 1 * AR_R); break;
        case 2: foldT_dev(Wk0, Arel + (l * 3 + 1) * HDD, L + 2 * AR_R); break;
        case 3: cvtT_dev(Wq + (l * 2 + 1) * CC, L + 3 * AR_R); break;
        case 4: foldT_dev(Wk1, Arel + (l * 3 + 2) * HDD, L + 4 * AR_R); break;
        case 5: foldT_dev(Wv0, Mrel + (l * 3 + 0) * HDD, L + 5 * AR_R); break;
        case 6: foldT_dev(Wv0, Mrel + (l * 3 + 1) * HDD, L + 6 * AR_R); break;
        case 7: foldT_dev(Wv1, Mrel + (l * 3 + 2) * HDD, L + 7 * AR_R); break;
        case 8: cvtT_dev(Wa + (l * 2 + 0) * CC, L + 8 * AR_R); break;
        case 9: cvtT_dev(Wa + (l * 2 + 1) * CC, L + 9 * AR_R); break;
    }
}

__global__ __launch_bounds__(256) void prep_stack_k(const float* __restrict__ Wsh,
                                                    _Float16* __restrict__ SA) {
    cvtT_dev(Wsh + (size_t)blockIdx.y * 65536, SA + (size_t)blockIdx.y * AR_R);
}

__global__ __launch_bounds__(256) void prep_heads_k(const float* __restrict__ Wt1,
                                                    _Float16* __restrict__ HA) {
    const int o = blockIdx.x, k = blockIdx.y, c = threadIdx.x;
    HA[(size_t)(k * 128 + o) * 256 + c] =
        (_Float16)Wt1[(size_t)k * 256 * 128 + (size_t)c * 128 + o];
}

// ---------------------------------------------------------------------------
// fp16 MFMA GEMM body (BK=64; global_load_lds width=16, pre-swizzled source).
// ---------------------------------------------------------------------------
template <int EPI, bool SPLIT>
__device__ __forceinline__ void gemm_body(
    const _Float16* __restrict__ A, const _Float16* __restrict__ Bt,
    _Float16* __restrict__ C, int M, int Nc, int bm, int bn, size_t bufStride,
    const float* __restrict__ bias, const float* __restrict__ skipv,
    _Float16* As, _Float16* Bs) {
    const int tid = threadIdx.x;
    const int wave = tid >> 6, lane = tid & 63;
    const int wm = (wave >> 1) * 64, wn = (wave & 1) * 64;
    const int l15 = lane & 15, g = lane >> 4;

    f32x4 acc[4][4] = {};

    for (int k0 = 0; k0 < 256; k0 += 64) {
        __syncthreads();
#pragma unroll
        for (int p = 0; p < 4; ++p) {
            const int slot = p * 256 + tid;
            const int r = slot >> 3;
            const int cb = ((slot & 7) << 4) ^ ((r & 7) << 4);
            int gr = bm + r; if (gr >= M) gr = M - 1;
            __builtin_amdgcn_global_load_lds(
                (const __attribute__((address_space(1))) void*)
                    ((const char*)A + ((size_t)gr * 256 + k0) * 2 + cb),
                (__attribute__((address_space(3))) void*)((char*)As + slot * 16),
                16, 0, 0);
            __builtin_amdgcn_global_load_lds(
                (const __attribute__((address_space(1))) void*)
                    ((const char*)Bt + ((size_t)(bn + r) * 256 + k0) * 2 + cb),
                (__attribute__((address_space(3))) void*)((char*)Bs + slot * 16),
                16, 0, 0);
        }
        __syncthreads();
#pragma unroll
        for (int sub = 0; sub < 2; ++sub) {
            f16x8 af[4], bf[4];
#pragma unroll
            for (int i = 0; i < 4; ++i) {
                const int ra = wm + i * 16 + l15;
                const int rb = wn + i * 16 + l15;
                const int ka = (sub * 64 + g * 16) ^ ((ra & 7) << 4);
                const int kb = (sub * 64 + g * 16) ^ ((rb & 7) << 4);
                af[i] = *(const f16x8*)((const char*)As + ra * 128 + ka);
                bf[i] = *(const f16x8*)((const char*)Bs + rb * 128 + kb);
            }
#pragma unroll
            for (int mi = 0; mi < 4; ++mi)
#pragma unroll
                for (int ni = 0; ni < 4; ++ni)
                    acc[mi][ni] = __builtin_amdgcn_mfma_f32_16x16x32_f16(
                        af[mi], bf[ni], acc[mi][ni], 0, 0, 0);
        }
    }

    float be = 0.f, ombe = 0.f;
    if (EPI == 1) {
        const float s = skipv[0];
        be = 1.0f / (1.0f + expf(-s));
        ombe = 1.0f - be;
    }
#pragma unroll
    for (int mi = 0; mi < 4; ++mi) {
#pragma unroll
        for (int r = 0; r < 4; ++r) {
            const int row = bm + wm + mi * 16 + g * 4 + r;
            if (row >= M) continue;
#pragma unroll
            for (int ni = 0; ni < 4; ++ni) {
                const int colg = bn + wn + ni * 16 + l15;
                float v = acc[mi][ni][r];
                size_t idx;
                if (SPLIT)
                    idx = (size_t)(colg >> 8) * bufStride + (size_t)row * 256 +
                          (colg & 255);
                else
                    idx = (size_t)row * Nc + colg;
                if (EPI == 1) v = be * v + ombe * (float)C[idx];
                if (EPI == 2) v = fmaxf(v + bias[colg], 0.f);
                C[idx] = (_Float16)v;
            }
        }
    }
}

template <int EPI, bool SPLIT>
__global__ __launch_bounds__(256) void gemm_h(
    const _Float16* __restrict__ A, const _Float16* __restrict__ Bt,
    _Float16* __restrict__ C, int M, int Nc, size_t bufStride,
    const float* __restrict__ bias, const float* __restrict__ skipv) {
    __shared__ _Float16 As[128 * 64];
    __shared__ _Float16 Bs[128 * 64];
    gemm_body<EPI, SPLIT>(A, Bt, C, M, Nc, blockIdx.y * 128, blockIdx.x * 128,
                          bufStride, bias, skipv, As, Bs);
}

// Q/K projection super-dispatch: 5 jobs x 2 col-panels, grid (10, gx).
__global__ __launch_bounds__(256) void projq_k(
    const _Float16* __restrict__ xeH, const _Float16* __restrict__ xsH,
    const _Float16* __restrict__ L, _Float16* __restrict__ Hb, int M) {
    __shared__ _Float16 As[128 * 64];
    __shared__ _Float16 Bs[128 * 64];
    const int job = blockIdx.x >> 1;
    const int bn = (blockIdx.x & 1) * 128;
    const _Float16* A = (job < 3) ? xeH : xsH;
    const _Float16* Bt = L + (size_t)job * AR_R;
    _Float16* C = Hb + (size_t)job * (size_t)M * 256;
    gemm_body<0, false>(A, Bt, C, M, 256, blockIdx.y * 128, bn, 0, nullptr,
                        nullptr, As, Bs);
}

// V projection super-dispatch: 3 jobs, grid (6, gx).
__global__ __launch_bounds__(256) void projv_k(
    const _Float16* __restrict__ xeH, const _Float16* __restrict__ xsH,
    const _Float16* __restrict__ L, _Float16* __restrict__ Hb, int M) {
    __shared__ _Float16 As[128 * 64];
    __shared__ _Float16 Bs[128 * 64];
    const int job = blockIdx.x >> 1;
    const int bn = (blockIdx.x & 1) * 128;
    const _Float16* A = (job < 2) ? xeH : xsH;
    const _Float16* Bt = L + (size_t)(5 + job) * AR_R;
    const int dsti = (job == 0) ? 1 : (job == 1) ? 2 : 4;
    _Float16* C = Hb + (size_t)dsti * (size_t)M * 256;
    gemm_body<0, false>(A, Bt, C, M, 256, blockIdx.y * 128, bn, 0, nullptr,
                        nullptr, As, Bs);
}

// Fused skip-updates; grid = (4, row_panels).
__global__ __launch_bounds__(256) void update2_k(
    const _Float16* __restrict__ aggE, const _Float16* __restrict__ aggS,
    const _Float16* __restrict__ WaT0, const _Float16* __restrict__ WaT1,
    _Float16* __restrict__ xeH, _Float16* __restrict__ xsH,
    const float* __restrict__ skipb, int M) {
    __shared__ _Float16 As[128 * 64];
    __shared__ _Float16 Bs[128 * 64];
    const int sel = blockIdx.x >> 1;
    const int bn = (blockIdx.x & 1) * 128;
    const int bm = blockIdx.y * 128;
    if (sel == 0)
        gemm_body<1, false>(aggE, WaT0, xeH, M, 256, bm, bn, 0, nullptr, skipb,
                            As, Bs);
    else
        gemm_body<1, false>(aggS, WaT1, xsH, M, 256, bm, bn, 0, nullptr,
                            skipb + 1, As, Bs);
}

// ---------------------------------------------------------------------------
// CSR build: hist -> 3-phase parallel scan -> scatter (colsrc).
// ---------------------------------------------------------------------------
__global__ __launch_bounds__(256) void hist3_k(const int* __restrict__ d0,
                                               const int* __restrict__ d1,
                                               const int* __restrict__ d2,
                                               int* __restrict__ cnt, int N,
                                               int E) {
    const int i = blockIdx.x * 256 + threadIdx.x;
    if (i >= E) return;
    const int r = blockIdx.y;
    const int* d = r == 0 ? d0 : r == 1 ? d1 : d2;
    atomicAdd(&cnt[(size_t)r * N + d[i]], 1);
}

__global__ __launch_bounds__(256) void partial_k(const int* __restrict__ cnt,
                                                 int* __restrict__ partials,
                                                 int N, int PB) {
    const int r = blockIdx.y, b = blockIdx.x, tid = threadIdx.x;
    const int gi = b * 256 + tid;
    int v = (gi < N) ? cnt[(size_t)r * N + gi] : 0;
#pragma unroll
    for (int o = 1; o < 64; o <<= 1) v += __shfl_xor(v, o);
    __shared__ int ws[4];
    if ((tid & 63) == 0) ws[tid >> 6] = v;
    __syncthreads();
    if (tid == 0) partials[r * PB + b] = ws[0] + ws[1] + ws[2] + ws[3];
}

__global__ __launch_bounds__(256) void scanp_k(int* __restrict__ partials,
                                               int* __restrict__ rp, int N,
                                               int PB, int E) {
    __shared__ int lds[256];
    const int r = blockIdx.y, tid = threadIdx.x;
    const int v = (tid < PB) ? partials[r * PB + tid] : 0;
    lds[tid] = v;
    __syncthreads();
    int acc = v;
    for (int off = 1; off < 256; off <<= 1) {
        const int t = (tid >= off) ? lds[tid - off] : 0;
        __syncthreads();
        acc += t;
        lds[tid] = acc;
        __syncthreads();
    }
    if (tid < PB) partials[r * PB + tid] = acc - v;
    if (tid == 0) rp[(size_t)r * (N + 1) + N] = E;
}

__global__ __launch_bounds__(256) void rpwrite_k(const int* __restrict__ cnt,
                                                 const int* __restrict__ partials,
                                                 int* __restrict__ rp, int N,
                                                 int PB) {
    __shared__ int lds[256];
    const int r = blockIdx.y, b = blockIdx.x, tid = threadIdx.x;
    const int gi = b * 256 + tid;
    const int v = (gi < N) ? cnt[(size_t)r * N + gi] : 0;
    lds[tid] = v;
    __syncthreads();
    int acc = v;
    for (int off = 1; off < 256; off <<= 1) {
        const int t = (tid >= off) ? lds[tid - off] : 0;
        __syncthreads();
        acc += t;
        lds[tid] = acc;
        __syncthreads();
    }
    if (gi < N) rp[(size_t)r * (N + 1) + gi] = partials[r * PB + b] + acc - v;
}

__global__ __launch_bounds__(256) void scatter3_k(
    const int* __restrict__ d0, const int* __restrict__ d1,
    const int* __restrict__ d2, const int* __restrict__ s0_,
    const int* __restrict__ s1_, const int* __restrict__ s2_,
    const int* __restrict__ rp, int* __restrict__ fill,
    int* __restrict__ colsrc, int N, int E) {
    const int i = blockIdx.x * 256 + threadIdx.x;
    if (i >= E) return;
    const int r = blockIdx.y;
    const int* d = r == 0 ? d0 : r == 1 ? d1 : d2;
    const int* s = r == 0 ? s0_ : r == 1 ? s1_ : s2_;
    const int dd = d[i];
    const int p = rp[(size_t)r * (N + 1) + dd] + atomicAdd(&fill[(size_t)r * N + dd], 1);
    colsrc[(size_t)r * E + p] = s[i];
}

// ---------------------------------------------------------------------------
// Scoring: wave per dst; 16 lanes per edge, 4 edges in flight, 2x unrolled.
// ---------------------------------------------------------------------------
__device__ __forceinline__ void score_rel_g(
    const f16x8 q0, const f16x8 q1, const _Float16* __restrict__ kA,
    const int* __restrict__ cs, int beg, int end, float scl,
    float* __restrict__ sc, int grp, int j, float& m) {
    int i = beg + grp;
    for (; i + 4 < end; i += 8) {
        const int sA = cs[i], sB = cs[i + 4];
        const _Float16* rowA = &kA[(size_t)sA * 256 + j * 16];
        const _Float16* rowB = &kA[(size_t)sB * 256 + j * 16];
        const f16x8 a0 = *(const f16x8*)rowA;
        const f16x8 a1 = *(const f16x8*)(rowA + 8);
        const f16x8 b0 = *(const f16x8*)rowB;
        const f16x8 b1 = *(const f16x8*)(rowB + 8);
        float p0 = dot8f(q1, a1, dot8f(q0, a0, 0.f));
        float p1 = dot8f(q1, b1, dot8f(q0, b0, 0.f));
        p0 += __shfl_xor(p0, 1); p1 += __shfl_xor(p1, 1);
        p0 += __shfl_xor(p0, 2); p1 += __shfl_xor(p1, 2);
        const float v0 = p0 * scl, v1 = p1 * scl;
        if ((j & 3) == 0) {
            sc[(size_t)i * 4 + (j >> 2)] = v0;
            sc[(size_t)(i + 4) * 4 + (j >> 2)] = v1;
            m = fmaxf(m, fmaxf(v0, v1));
        }
    }
    if (i < end) {
        const int sA = cs[i];
        const _Float16* row = &kA[(size_t)sA * 256 + j * 16];
        const f16x8 k0 = *(const f16x8*)row;
        const f16x8 k1 = *(const f16x8*)(row + 8);
        float p = dot8f(q1, k1, dot8f(q0, k0, 0.f));
        p += __shfl_xor(p, 1);
        p += __shfl_xor(p, 2);
        const float v = p * scl;
        if ((j & 3) == 0) {
            sc[(size_t)i * 4 + (j >> 2)] = v;
            m = fmaxf(m, v);
        }
    }
}

__global__ __launch_bounds__(256) void score3_k(
    const _Float16* __restrict__ qe, const _Float16* __restrict__ kA0,
    const _Float16* __restrict__ kA1, const _Float16* __restrict__ qs,
    const _Float16* __restrict__ kA2, const int* __restrict__ rp,
    const int* __restrict__ colsrc, const float* __restrict__ muL,
    float* __restrict__ sc, float* __restrict__ mx_e,
    float* __restrict__ mx_s, int N, int E) {
    const int wid = (blockIdx.x * blockDim.x + threadIdx.x) >> 6;
    if (wid >= N) return;
    const int lane = threadIdx.x & 63;
    const int grp = lane >> 4, j = lane & 15, h = j >> 2;
    const size_t E4 = (size_t)E * 4;
    float m = -1e30f;
    if (blockIdx.y == 0) {
        const _Float16* qrow = &qe[(size_t)wid * 256 + j * 16];
        const f16x8 q0 = *(const f16x8*)qrow;
        const f16x8 q1 = *(const f16x8*)(qrow + 8);
        score_rel_g(q0, q1, kA0, colsrc, rp[wid], rp[wid + 1],
                    muL[0 * 4 + h] * 0.125f, sc, grp, j, m);
        const int* rp2 = rp + 2 * (N + 1);
        score_rel_g(q0, q1, kA2, colsrc + 2 * (size_t)E, rp2[wid], rp2[wid + 1],
                    muL[2 * 4 + h] * 0.125f, sc + 2 * E4, grp, j, m);
        m = fmaxf(m, __shfl_xor(m, 16));
        m = fmaxf(m, __shfl_xor(m, 32));
        if (grp == 0 && (j & 3) == 0) mx_e[(size_t)wid * 4 + h] = m;
    } else {
        const _Float16* qrow = &qs[(size_t)wid * 256 + j * 16];
        const f16x8 q0 = *(const f16x8*)qrow;
        const f16x8 q1 = *(const f16x8*)(qrow + 8);
        const int* rp1 = rp + (N + 1);
        score_rel_g(q0, q1, kA1, colsrc + (size_t)E, rp1[wid], rp1[wid + 1],
                    muL[1 * 4 + h] * 0.125f, sc + E4, grp, j, m);
        m = fmaxf(m, __shfl_xor(m, 16));
        m = fmaxf(m, __shfl_xor(m, 32));
        if (grp == 0 && (j & 3) == 0) mx_s[(size_t)wid * 4 + h] = m;
    }
}

// ---------------------------------------------------------------------------
// Aggregation (single-pass online, __expf, 2x unrolled): w = exp(s-m);
// den += w; acc += w*v. Cross-group combine, normalize, distributed GELU.
// ---------------------------------------------------------------------------
__device__ __forceinline__ void agg_rel_on(
    const float* __restrict__ sc, const _Float16* __restrict__ vM,
    const int* __restrict__ cs, int beg, int end, float mh, int grp, int j,
    int h, float* accf, float& den) {
    int i = beg + grp;
    for (; i + 4 < end; i += 8) {
        const int sA = cs[i], sB = cs[i + 4];
        const float w0 = __expf(sc[(size_t)i * 4 + h] - mh);
        const float w1 = __expf(sc[(size_t)(i + 4) * 4 + h] - mh);
        const _Float16* rowA = &vM[(size_t)sA * 256 + j * 16];
        const _Float16* rowB = &vM[(size_t)sB * 256 + j * 16];
        const f16x8 a0 = *(const f16x8*)rowA;
        const f16x8 a1 = *(const f16x8*)(rowA + 8);
        const f16x8 b0 = *(const f16x8*)rowB;
        const f16x8 b1 = *(const f16x8*)(rowB + 8);
        den += w0 + w1;
#pragma unroll
        for (int t = 0; t < 8; ++t)
            accf[t] += w0 * (float)a0[t] + w1 * (float)b0[t];
#pragma unroll
        for (int t = 0; t < 8; ++t)
            accf[8 + t] += w0 * (float)a1[t] + w1 * (float)b1[t];
    }
    if (i < end) {
        const int sA = cs[i];
        const float w = __expf(sc[(size_t)i * 4 + h] - mh);
        den += w;
        const _Float16* row = &vM[(size_t)sA * 256 + j * 16];
        const f16x8 v0 = *(const f16x8*)row;
        const f16x8 v1 = *(const f16x8*)(row + 8);
#pragma unroll
        for (int t = 0; t < 8; ++t) accf[t] += w * (float)v0[t];
#pragma unroll
        for (int t = 0; t < 8; ++t) accf[8 + t] += w * (float)v1[t];
    }
}

__global__ __launch_bounds__(256) void agg3_k(
    const float* __restrict__ sc, const _Float16* __restrict__ vM0,
    const _Float16* __restrict__ vM1, const _Float16* __restrict__ vM2,
    const int* __restrict__ rp, const int* __restrict__ colsrc,
    const float* __restrict__ mx_e, const float* __restrict__ mx_s,
    _Float16* __restrict__ outE, _Float16* __restrict__ outS, int N, int E) {
    const int wid = (blockIdx.x * blockDim.x + threadIdx.x) >> 6;
    if (wid >= N) return;
    const int lane = threadIdx.x & 63;
    const int grp = lane >> 4, j = lane & 15, h = j >> 2;
    const size_t E4 = (size_t)E * 4;
    float accf[16] = {};
    float den = 0.f;
    _Float16* outp;
    if (blockIdx.y == 0) {
        const float mh = mx_e[(size_t)wid * 4 + h];
        const int b0 = rp[wid], e0 = rp[wid + 1];
        const int* rp2 = rp + 2 * (N + 1);
        const int b2 = rp2[wid], e2 = rp2[wid + 1];
        agg_rel_on(sc, vM0, colsrc, b0, e0, mh, grp, j, h, accf, den);
        agg_rel_on(sc + 2 * E4, vM2, colsrc + 2 * (size_t)E, b2, e2, mh, grp,
                   j, h, accf, den);
        outp = outE;
    } else {
        const float mh = mx_s[(size_t)wid * 4 + h];
        const int* rp1 = rp + (N + 1);
        const int b1 = rp1[wid], e1 = rp1[wid + 1];
        agg_rel_on(sc + E4, vM1, colsrc + (size_t)E, b1, e1, mh, grp, j, h,
                   accf, den);
        outp = outS;
    }
    den += __shfl_xor(den, 16);
    den += __shfl_xor(den, 32);
#pragma unroll
    for (int t = 0; t < 16; ++t) {
        accf[t] += __shfl_xor(accf[t], 16);
        accf[t] += __shfl_xor(accf[t], 32);
    }
    const float dinv = 1.0f / (den + 1e-16f);
    f16x4 o;
#pragma unroll
    for (int t = 0; t < 4; ++t)
        o[t] = (_Float16)gelu_f(accf[grp * 4 + t] * dinv);
    *(f16x4*)&outp[(size_t)wid * 256 + j * 16 + grp * 4] = o;
}

// ---------------------------------------------------------------------------
// Batched head epilogue.
// ---------------------------------------------------------------------------
__global__ __launch_bounds__(256) void head2_k(const _Float16* __restrict__ t,
                                               const float* __restrict__ Wt2,
                                               const float* __restrict__ bt2,
                                               float* __restrict__ out, int M) {
    const int k = blockIdx.y;
    __shared__ float Ws[128 * 8];
    __shared__ float bs[8];
    const int tid = threadIdx.x;
    const float* W2 = Wt2 + (size_t)k * 1024;
    for (int i = tid; i < 1024; i += 256) Ws[i] = W2[i];
    if (tid < 8) bs[tid] = bt2[k * 8 + tid];
    __syncthreads();
    const int OFFA[7] = {0, 3, 6, 9, 14, 15, 16};
    const int DIMSA[7] = {3, 3, 3, 5, 1, 1, 8};
    const int nl = tid >> 3, o = tid & 7;
    const int n = blockIdx.x * 32 + nl;
    if (n >= M) return;
    const _Float16* tr = &t[(size_t)n * 896 + k * 128];
    float acc = bs[o];
#pragma unroll 8
    for (int d = 0; d < 128; ++d) acc += (float)tr[d] * Ws[d * 8 + o];
    if (o < DIMSA[k]) out[(size_t)n * 24 + OFFA[k] + o] = acc;
}

// ---------------------------------------------------------------------------

extern "C" void kernel_launch(void* const* d_in, const int* in_sizes, int n_in,
                              void* d_out, int out_size, void* d_ws,
                              size_t ws_size, hipStream_t stream) {
    const float* xe_in = (const float*)d_in[0];
    const float* xs_in = (const float*)d_in[1];
    const int* ee_src = (const int*)d_in[2];
    const int* ee_dst = (const int*)d_in[3];
    const int* es_src = (const int*)d_in[4];
    const int* es_dst = (const int*)d_in[5];
    const int* se_src = (const int*)d_in[6];
    const int* se_dst = (const int*)d_in[7];
    const float* Wk = (const float*)d_in[8];
    const float* Wq = (const float*)d_in[9];
    const float* Wv = (const float*)d_in[10];
    const float* Wa = (const float*)d_in[11];
    const float* skip = (const float*)d_in[12];
    const float* Arel = (const float*)d_in[13];
    const float* Mrel = (const float*)d_in[14];
    const float* mu = (const float*)d_in[15];
    const float* Wsh = (const float*)d_in[16];
    const float* bsh = (const float*)d_in[17];
    const float* Wt1 = (const float*)d_in[18];
    const float* bt1 = (const float*)d_in[19];
    const float* Wt2 = (const float*)d_in[20];
    const float* bt2 = (const float*)d_in[21];
    float* out = (float*)d_out;

    const int N = in_sizes[0] / CDIM;  // 50000
    const int E = in_sizes[2];         // 200000
    const size_t NC = (size_t)N * CDIM;
    const size_t E4 = (size_t)E * 4;
    const size_t N4 = (size_t)N * 4;
    const int PB = (N + 255) / 256;

    const size_t halfs = 7 * NC + 32 * (size_t)AR_R + 7 * 32768;
    const size_t floats = 3 * E4 + 2 * N4;
    const size_t ints =
        3 * (size_t)(N + 1) + 3 * (size_t)E + 3 * (size_t)N + 3 * (size_t)PB;
    const size_t need = halfs * 2 + floats * 4 + ints * 4;
    if (ws_size < need) return;

    _Float16* xeH = (_Float16*)d_ws;
    _Float16* xsH = xeH + NC;
    _Float16* Hb = xsH + NC;
    _Float16* H1 = Hb;
    _Float16* H2 = Hb + NC;
    _Float16* H3 = Hb + 2 * NC;
    _Float16* H4 = Hb + 3 * NC;
    _Float16* H5 = Hb + 4 * NC;
    _Float16* arena = Hb + 5 * NC;
    _Float16* SA = arena + (size_t)30 * AR_R;
    _Float16* HA = SA + (size_t)2 * AR_R;
    float* sc = (float*)(HA + (size_t)7 * 32768);
    float* mx_e = sc + 3 * E4;
    float* mx_s = mx_e + N4;
    int* rp = (int*)(mx_s + N4);
    int* colsrc = rp + 3 * (size_t)(N + 1);
    int* cnt = colsrc + 3 * (size_t)E;
    int* partials = cnt + 3 * (size_t)N;

    const int gx = (N + 127) / 128;
    const dim3 e3((E + 255) / 256, 3);
    const dim3 p3(PB, 3);
    const int wave_blocks = (N + 3) / 4;
    const int zc_blocks = (3 * N + 255) / 256;

    // ---- CSR build ----
    zero_k<<<zc_blocks, 256, 0, stream>>>(cnt, 3 * (size_t)N);
    hist3_k<<<e3, 256, 0, stream>>>(ee_dst, es_dst, se_dst, cnt, N, E);
    partial_k<<<p3, 256, 0, stream>>>(cnt, partials, N, PB);
    scanp_k<<<dim3(1, 3), 256, 0, stream>>>(partials, rp, N, PB, E);
    rpwrite_k<<<p3, 256, 0, stream>>>(cnt, partials, rp, N, PB);
    zero_k<<<zc_blocks, 256, 0, stream>>>(cnt, 3 * (size_t)N);
    scatter3_k<<<e3, 256, 0, stream>>>(ee_dst, es_dst, se_dst, ee_src, es_src,
                                       se_src, rp, cnt, colsrc, N, E);

    // ---- weight prep ----
    prep_layer_k<<<dim3(256, 30), 256, 0, stream>>>(Wk, Wq, Wv, Wa, Arel, Mrel,
                                                    arena);
    prep_stack_k<<<dim3(256, 2), 256, 0, stream>>>(Wsh, SA);
    prep_heads_k<<<dim3(128, 7), 256, 0, stream>>>(Wt1, HA);

    // ---- initial fp16 activations ----
    cvt2_k<<<dim3(1024, 2), 256, 0, stream>>>(xe_in, xs_in, xeH, xsH, NC / 4);

    for (int l = 0; l < 3; ++l) {
        _Float16* L = arena + (size_t)l * 10 * AR_R;
        projq_k<<<dim3(10, gx), 256, 0, stream>>>(xeH, xsH, L, Hb, N);
        score3_k<<<dim3(wave_blocks, 2), 256, 0, stream>>>(
            H1, H2, H3, H4, H5, rp, colsrc, mu + l * 12, sc, mx_e, mx_s, N, E);
        projv_k<<<dim3(6, gx), 256, 0, stream>>>(xeH, xsH, L, Hb, N);
        agg3_k<<<dim3(wave_blocks, 2), 256, 0, stream>>>(
            sc, H2, H3, H5, rp, colsrc, mx_e, mx_s, H1, H4, N, E);
        update2_k<<<dim3(4, gx), 256, 0, stream>>>(
            H1, H4, L + 8 * AR_R, L + 9 * AR_R, xeH, xsH, skip + l * 2, N);
    }

    // shared linear stack
    gemm_h<2, false><<<dim3(2, gx), 256, 0, stream>>>(xeH, SA, H5, N, 256, 0,
                                                      bsh, nullptr);
    gemm_h<2, false><<<dim3(2, gx), 256, 0, stream>>>(H5, SA + AR_R, xsH, N,
                                                      256, 0, bsh + 256, nullptr);
    // 7 task heads
    gemm_h<2, false><<<dim3(7, gx), 256, 0, stream>>>(xsH, HA, Hb, N, 896, 0,
                                                      bt1, nullptr);
    head2_k<<<dim3((N + 31) / 32, 7), 256, 0, stream>>>(Hb, Wt2, bt2, out, N);
}

// Round 15
// 1041.425 us; speedup vs baseline: 1.1541x; 1.0327x over previous
//
#include <hip/hip_runtime.h>
#include <hip/hip_fp16.h>
#include <cmath>

// ---------------------------------------------------------------------------
// DragonHGT R15: R12 structure; score3 keeps R14's 2x unroll (A/B positive),
// agg3 reverted to R12's no-unroll form (R14's unroll cost -11.5us/dispatch).
// fp16 MFMA GEMMs (BK=64, XOR LDS via pre-swizzled global_load_lds),
// CSR edge pipeline, parallel 3-phase scan, consolidated dispatches.
// N=50000 x 2 node types, E=200000 x 3 relations, C=256 (H=4, D=64).
// ---------------------------------------------------------------------------

#define CDIM 256
#define AR_R (256 * 256)

using f16x8 = __attribute__((ext_vector_type(8))) _Float16;
using f16x4 = __attribute__((ext_vector_type(4))) _Float16;
using f16x2 = __attribute__((ext_vector_type(2))) _Float16;
using f32x4 = __attribute__((ext_vector_type(4))) float;

__device__ __forceinline__ float gelu_f(float x) {
    return 0.5f * x * (1.0f + erff(x * 0.70710678118654752f));
}

__device__ __forceinline__ float dot8f(const f16x8 a, const f16x8 b, float r) {
#if __has_builtin(__builtin_amdgcn_fdot2)
#pragma unroll
    for (int t = 0; t < 4; ++t) {
        f16x2 av = {a[2 * t], a[2 * t + 1]};
        f16x2 bv = {b[2 * t], b[2 * t + 1]};
        r = __builtin_amdgcn_fdot2(av, bv, r, false);
    }
#else
#pragma unroll
    for (int t = 0; t < 8; ++t) r += (float)a[t] * (float)b[t];
#endif
    return r;
}

__global__ __launch_bounds__(256) void zero_k(int* __restrict__ p, size_t n) {
    size_t i = (size_t)blockIdx.x * blockDim.x + threadIdx.x;
    const size_t stride = (size_t)gridDim.x * blockDim.x;
    for (; i < n; i += stride) p[i] = 0;
}

__global__ __launch_bounds__(256) void cvt2_k(const float* __restrict__ xe_in,
                                              const float* __restrict__ xs_in,
                                              _Float16* __restrict__ xeH,
                                              _Float16* __restrict__ xsH,
                                              size_t n4) {
    const float* in = blockIdx.y ? xs_in : xe_in;
    _Float16* out = blockIdx.y ? xsH : xeH;
    size_t i = (size_t)blockIdx.x * blockDim.x + threadIdx.x;
    const size_t stride = (size_t)gridDim.x * blockDim.x;
    for (; i < n4; i += stride) {
        const float4 v = ((const float4*)in)[i];
        f16x4 o;
        o[0] = (_Float16)v.x; o[1] = (_Float16)v.y;
        o[2] = (_Float16)v.z; o[3] = (_Float16)v.w;
        ((f16x4*)out)[i] = o;
    }
}

// ---------------------------------------------------------------------------
// Weight prep (single dispatch for all 3 layers).
// ---------------------------------------------------------------------------
__device__ __forceinline__ void cvtT_dev(const float* __restrict__ W,
                                         _Float16* __restrict__ dst) {
    const int o = blockIdx.x, c = threadIdx.x;
    dst[(size_t)o * 256 + c] = (_Float16)W[(size_t)c * 256 + o];
}

__device__ __forceinline__ void foldT_dev(const float* __restrict__ Wbase,
                                          const float* __restrict__ T,
                                          _Float16* __restrict__ dst) {
    __shared__ float row[256];
    const int c = blockIdx.x, t = threadIdx.x;
    row[t] = Wbase[(size_t)c * 256 + t];
    __syncthreads();
    const int h = t >> 6, f = t & 63;
    const float* Th = T + h * 4096;
    float acc = 0.f;
#pragma unroll 8
    for (int d = 0; d < 64; ++d) acc += row[h * 64 + d] * Th[d * 64 + f];
    dst[(size_t)t * 256 + c] = (_Float16)acc;
}

// arena per layer: [0]q_e [1]kA0 [2]kA1 [3]q_s [4]kA2 [5]vM0 [6]vM1 [7]vM2
//                  [8]WaT0 [9]WaT1
__global__ __launch_bounds__(256) void prep_layer_k(
    const float* __restrict__ Wk, const float* __restrict__ Wq,
    const float* __restrict__ Wv, const float* __restrict__ Wa,
    const float* __restrict__ Arel, const float* __restrict__ Mrel,
    _Float16* __restrict__ arena) {
    const size_t CC = 65536, HDD = 16384;
    const int l = blockIdx.y / 10;
    const int c = blockIdx.y % 10;
    _Float16* L = arena + (size_t)l * 10 * AR_R;
    const float* Wk0 = Wk + (l * 2 + 0) * CC;
    const float* Wk1 = Wk + (l * 2 + 1) * CC;
    const float* Wv0 = Wv + (l * 2 + 0) * CC;
    const float* Wv1 = Wv + (l * 2 + 1) * CC;
    switch (c) {
        case 0: cvtT_dev(Wq + (l * 2 + 0) * CC, L); break;
        case 1: foldT_dev(Wk0, Arel + (l * 3 + 0) * HDD, L + 1 * AR_R); break;
        case 2: foldT_dev(Wk0, Arel + (l * 3 + 1) * HDD, L + 2 * AR_R); break;
        case 3: cvtT_dev(Wq + (l * 2 + 1) * CC, L + 3 * AR_R); break;
        case 4: foldT_dev(Wk1, Arel + (l * 3 + 2) * HDD, L + 4 * AR_R); break;
        case 5: foldT_dev(Wv0, Mrel + (l * 3 + 0) * HDD, L + 5 * AR_R); break;
        case 6: foldT_dev(Wv0, Mrel + (l * 3 + 1) * HDD, L + 6 * AR_R); break;
        case 7: foldT_dev(Wv1, Mrel + (l * 3 + 2) * HDD, L + 7 * AR_R); break;
        case 8: cvtT_dev(Wa + (l * 2 + 0) * CC, L + 8 * AR_R); break;
        case 9: cvtT_dev(Wa + (l * 2 + 1) * CC, L + 9 * AR_R); break;
    }
}

__global__ __launch_bounds__(256) void prep_stack_k(const float* __restrict__ Wsh,
                                                    _Float16* __restrict__ SA) {
    cvtT_dev(Wsh + (size_t)blockIdx.y * 65536, SA + (size_t)blockIdx.y * AR_R);
}

__global__ __launch_bounds__(256) void prep_heads_k(const float* __restrict__ Wt1,
                                                    _Float16* __restrict__ HA) {
    const int o = blockIdx.x, k = blockIdx.y, c = threadIdx.x;
    HA[(size_t)(k * 128 + o) * 256 + c] =
        (_Float16)Wt1[(size_t)k * 256 * 128 + (size_t)c * 128 + o];
}

// ---------------------------------------------------------------------------
// fp16 MFMA GEMM body (BK=64; global_load_lds width=16, pre-swizzled source).
// ---------------------------------------------------------------------------
template <int EPI, bool SPLIT>
__device__ __forceinline__ void gemm_body(
    const _Float16* __restrict__ A, const _Float16* __restrict__ Bt,
    _Float16* __restrict__ C, int M, int Nc, int bm, int bn, size_t bufStride,
    const float* __restrict__ bias, const float* __restrict__ skipv,
    _Float16* As, _Float16* Bs) {
    const int tid = threadIdx.x;
    const int wave = tid >> 6, lane = tid & 63;
    const int wm = (wave >> 1) * 64, wn = (wave & 1) * 64;
    const int l15 = lane & 15, g = lane >> 4;

    f32x4 acc[4][4] = {};

    for (int k0 = 0; k0 < 256; k0 += 64) {
        __syncthreads();
#pragma unroll
        for (int p = 0; p < 4; ++p) {
            const int slot = p * 256 + tid;
            const int r = slot >> 3;
            const int cb = ((slot & 7) << 4) ^ ((r & 7) << 4);
            int gr = bm + r; if (gr >= M) gr = M - 1;
            __builtin_amdgcn_global_load_lds(
                (const __attribute__((address_space(1))) void*)
                    ((const char*)A + ((size_t)gr * 256 + k0) * 2 + cb),
                (__attribute__((address_space(3))) void*)((char*)As + slot * 16),
                16, 0, 0);
            __builtin_amdgcn_global_load_lds(
                (const __attribute__((address_space(1))) void*)
                    ((const char*)Bt + ((size_t)(bn + r) * 256 + k0) * 2 + cb),
                (__attribute__((address_space(3))) void*)((char*)Bs + slot * 16),
                16, 0, 0);
        }
        __syncthreads();
#pragma unroll
        for (int sub = 0; sub < 2; ++sub) {
            f16x8 af[4], bf[4];
#pragma unroll
            for (int i = 0; i < 4; ++i) {
                const int ra = wm + i * 16 + l15;
                const int rb = wn + i * 16 + l15;
                const int ka = (sub * 64 + g * 16) ^ ((ra & 7) << 4);
                const int kb = (sub * 64 + g * 16) ^ ((rb & 7) << 4);
                af[i] = *(const f16x8*)((const char*)As + ra * 128 + ka);
                bf[i] = *(const f16x8*)((const char*)Bs + rb * 128 + kb);
            }
#pragma unroll
            for (int mi = 0; mi < 4; ++mi)
#pragma unroll
                for (int ni = 0; ni < 4; ++ni)
                    acc[mi][ni] = __builtin_amdgcn_mfma_f32_16x16x32_f16(
                        af[mi], bf[ni], acc[mi][ni], 0, 0, 0);
        }
    }

    float be = 0.f, ombe = 0.f;
    if (EPI == 1) {
        const float s = skipv[0];
        be = 1.0f / (1.0f + expf(-s));
        ombe = 1.0f - be;
    }
#pragma unroll
    for (int mi = 0; mi < 4; ++mi) {
#pragma unroll
        for (int r = 0; r < 4; ++r) {
            const int row = bm + wm + mi * 16 + g * 4 + r;
            if (row >= M) continue;
#pragma unroll
            for (int ni = 0; ni < 4; ++ni) {
                const int colg = bn + wn + ni * 16 + l15;
                float v = acc[mi][ni][r];
                size_t idx;
                if (SPLIT)
                    idx = (size_t)(colg >> 8) * bufStride + (size_t)row * 256 +
                          (colg & 255);
                else
                    idx = (size_t)row * Nc + colg;
                if (EPI == 1) v = be * v + ombe * (float)C[idx];
                if (EPI == 2) v = fmaxf(v + bias[colg], 0.f);
                C[idx] = (_Float16)v;
            }
        }
    }
}

template <int EPI, bool SPLIT>
__global__ __launch_bounds__(256) void gemm_h(
    const _Float16* __restrict__ A, const _Float16* __restrict__ Bt,
    _Float16* __restrict__ C, int M, int Nc, size_t bufStride,
    const float* __restrict__ bias, const float* __restrict__ skipv) {
    __shared__ _Float16 As[128 * 64];
    __shared__ _Float16 Bs[128 * 64];
    gemm_body<EPI, SPLIT>(A, Bt, C, M, Nc, blockIdx.y * 128, blockIdx.x * 128,
                          bufStride, bias, skipv, As, Bs);
}

// Q/K projection super-dispatch: 5 jobs x 2 col-panels, grid (10, gx).
__global__ __launch_bounds__(256) void projq_k(
    const _Float16* __restrict__ xeH, const _Float16* __restrict__ xsH,
    const _Float16* __restrict__ L, _Float16* __restrict__ Hb, int M) {
    __shared__ _Float16 As[128 * 64];
    __shared__ _Float16 Bs[128 * 64];
    const int job = blockIdx.x >> 1;
    const int bn = (blockIdx.x & 1) * 128;
    const _Float16* A = (job < 3) ? xeH : xsH;
    const _Float16* Bt = L + (size_t)job * AR_R;
    _Float16* C = Hb + (size_t)job * (size_t)M * 256;
    gemm_body<0, false>(A, Bt, C, M, 256, blockIdx.y * 128, bn, 0, nullptr,
                        nullptr, As, Bs);
}

// V projection super-dispatch: 3 jobs, grid (6, gx).
__global__ __launch_bounds__(256) void projv_k(
    const _Float16* __restrict__ xeH, const _Float16* __restrict__ xsH,
    const _Float16* __restrict__ L, _Float16* __restrict__ Hb, int M) {
    __shared__ _Float16 As[128 * 64];
    __shared__ _Float16 Bs[128 * 64];
    const int job = blockIdx.x >> 1;
    const int bn = (blockIdx.x & 1) * 128;
    const _Float16* A = (job < 2) ? xeH : xsH;
    const _Float16* Bt = L + (size_t)(5 + job) * AR_R;
    const int dsti = (job == 0) ? 1 : (job == 1) ? 2 : 4;
    _Float16* C = Hb + (size_t)dsti * (size_t)M * 256;
    gemm_body<0, false>(A, Bt, C, M, 256, blockIdx.y * 128, bn, 0, nullptr,
                        nullptr, As, Bs);
}

// Fused skip-updates; grid = (4, row_panels).
__global__ __launch_bounds__(256) void update2_k(
    const _Float16* __restrict__ aggE, const _Float16* __restrict__ aggS,
    const _Float16* __restrict__ WaT0, const _Float16* __restrict__ WaT1,
    _Float16* __restrict__ xeH, _Float16* __restrict__ xsH,
    const float* __restrict__ skipb, int M) {
    __shared__ _Float16 As[128 * 64];
    __shared__ _Float16 Bs[128 * 64];
    const int sel = blockIdx.x >> 1;
    const int bn = (blockIdx.x & 1) * 128;
    const int bm = blockIdx.y * 128;
    if (sel == 0)
        gemm_body<1, false>(aggE, WaT0, xeH, M, 256, bm, bn, 0, nullptr, skipb,
                            As, Bs);
    else
        gemm_body<1, false>(aggS, WaT1, xsH, M, 256, bm, bn, 0, nullptr,
                            skipb + 1, As, Bs);
}

// ---------------------------------------------------------------------------
// CSR build: hist -> 3-phase parallel scan -> scatter (colsrc).
// ---------------------------------------------------------------------------
__global__ __launch_bounds__(256) void hist3_k(const int* __restrict__ d0,
                                               const int* __restrict__ d1,
                                               const int* __restrict__ d2,
                                               int* __restrict__ cnt, int N,
                                               int E) {
    const int i = blockIdx.x * 256 + threadIdx.x;
    if (i >= E) return;
    const int r = blockIdx.y;
    const int* d = r == 0 ? d0 : r == 1 ? d1 : d2;
    atomicAdd(&cnt[(size_t)r * N + d[i]], 1);
}

__global__ __launch_bounds__(256) void partial_k(const int* __restrict__ cnt,
                                                 int* __restrict__ partials,
                                                 int N, int PB) {
    const int r = blockIdx.y, b = blockIdx.x, tid = threadIdx.x;
    const int gi = b * 256 + tid;
    int v = (gi < N) ? cnt[(size_t)r * N + gi] : 0;
#pragma unroll
    for (int o = 1; o < 64; o <<= 1) v += __shfl_xor(v, o);
    __shared__ int ws[4];
    if ((tid & 63) == 0) ws[tid >> 6] = v;
    __syncthreads();
    if (tid == 0) partials[r * PB + b] = ws[0] + ws[1] + ws[2] + ws[3];
}

__global__ __launch_bounds__(256) void scanp_k(int* __restrict__ partials,
                                               int* __restrict__ rp, int N,
                                               int PB, int E) {
    __shared__ int lds[256];
    const int r = blockIdx.y, tid = threadIdx.x;
    const int v = (tid < PB) ? partials[r * PB + tid] : 0;
    lds[tid] = v;
    __syncthreads();
    int acc = v;
    for (int off = 1; off < 256; off <<= 1) {
        const int t = (tid >= off) ? lds[tid - off] : 0;
        __syncthreads();
        acc += t;
        lds[tid] = acc;
        __syncthreads();
    }
    if (tid < PB) partials[r * PB + tid] = acc - v;
    if (tid == 0) rp[(size_t)r * (N + 1) + N] = E;
}

__global__ __launch_bounds__(256) void rpwrite_k(const int* __restrict__ cnt,
                                                 const int* __restrict__ partials,
                                                 int* __restrict__ rp, int N,
                                                 int PB) {
    __shared__ int lds[256];
    const int r = blockIdx.y, b = blockIdx.x, tid = threadIdx.x;
    const int gi = b * 256 + tid;
    const int v = (gi < N) ? cnt[(size_t)r * N + gi] : 0;
    lds[tid] = v;
    __syncthreads();
    int acc = v;
    for (int off = 1; off < 256; off <<= 1) {
        const int t = (tid >= off) ? lds[tid - off] : 0;
        __syncthreads();
        acc += t;
        lds[tid] = acc;
        __syncthreads();
    }
    if (gi < N) rp[(size_t)r * (N + 1) + gi] = partials[r * PB + b] + acc - v;
}

__global__ __launch_bounds__(256) void scatter3_k(
    const int* __restrict__ d0, const int* __restrict__ d1,
    const int* __restrict__ d2, const int* __restrict__ s0_,
    const int* __restrict__ s1_, const int* __restrict__ s2_,
    const int* __restrict__ rp, int* __restrict__ fill,
    int* __restrict__ colsrc, int N, int E) {
    const int i = blockIdx.x * 256 + threadIdx.x;
    if (i >= E) return;
    const int r = blockIdx.y;
    const int* d = r == 0 ? d0 : r == 1 ? d1 : d2;
    const int* s = r == 0 ? s0_ : r == 1 ? s1_ : s2_;
    const int dd = d[i];
    const int p = rp[(size_t)r * (N + 1) + dd] + atomicAdd(&fill[(size_t)r * N + dd], 1);
    colsrc[(size_t)r * E + p] = s[i];
}

// ---------------------------------------------------------------------------
// Scoring: wave per dst; 16 lanes per edge, 4 edges in flight, 2x unrolled
// (kept from R14 — A/B positive).
// ---------------------------------------------------------------------------
__device__ __forceinline__ void score_rel_g(
    const f16x8 q0, const f16x8 q1, const _Float16* __restrict__ kA,
    const int* __restrict__ cs, int beg, int end, float scl,
    float* __restrict__ sc, int grp, int j, float& m) {
    int i = beg + grp;
    for (; i + 4 < end; i += 8) {
        const int sA = cs[i], sB = cs[i + 4];
        const _Float16* rowA = &kA[(size_t)sA * 256 + j * 16];
        const _Float16* rowB = &kA[(size_t)sB * 256 + j * 16];
        const f16x8 a0 = *(const f16x8*)rowA;
        const f16x8 a1 = *(const f16x8*)(rowA + 8);
        const f16x8 b0 = *(const f16x8*)rowB;
        const f16x8 b1 = *(const f16x8*)(rowB + 8);
        float p0 = dot8f(q1, a1, dot8f(q0, a0, 0.f));
        float p1 = dot8f(q1, b1, dot8f(q0, b0, 0.f));
        p0 += __shfl_xor(p0, 1); p1 += __shfl_xor(p1, 1);
        p0 += __shfl_xor(p0, 2); p1 += __shfl_xor(p1, 2);
        const float v0 = p0 * scl, v1 = p1 * scl;
        if ((j & 3) == 0) {
            sc[(size_t)i * 4 + (j >> 2)] = v0;
            sc[(size_t)(i + 4) * 4 + (j >> 2)] = v1;
            m = fmaxf(m, fmaxf(v0, v1));
        }
    }
    if (i < end) {
        const int sA = cs[i];
        const _Float16* row = &kA[(size_t)sA * 256 + j * 16];
        const f16x8 k0 = *(const f16x8*)row;
        const f16x8 k1 = *(const f16x8*)(row + 8);
        float p = dot8f(q1, k1, dot8f(q0, k0, 0.f));
        p += __shfl_xor(p, 1);
        p += __shfl_xor(p, 2);
        const float v = p * scl;
        if ((j & 3) == 0) {
            sc[(size_t)i * 4 + (j >> 2)] = v;
            m = fmaxf(m, v);
        }
    }
}

__global__ __launch_bounds__(256) void score3_k(
    const _Float16* __restrict__ qe, const _Float16* __restrict__ kA0,
    const _Float16* __restrict__ kA1, const _Float16* __restrict__ qs,
    const _Float16* __restrict__ kA2, const int* __restrict__ rp,
    const int* __restrict__ colsrc, const float* __restrict__ muL,
    float* __restrict__ sc, float* __restrict__ mx_e,
    float* __restrict__ mx_s, int N, int E) {
    const int wid = (blockIdx.x * blockDim.x + threadIdx.x) >> 6;
    if (wid >= N) return;
    const int lane = threadIdx.x & 63;
    const int grp = lane >> 4, j = lane & 15, h = j >> 2;
    const size_t E4 = (size_t)E * 4;
    float m = -1e30f;
    if (blockIdx.y == 0) {
        const _Float16* qrow = &qe[(size_t)wid * 256 + j * 16];
        const f16x8 q0 = *(const f16x8*)qrow;
        const f16x8 q1 = *(const f16x8*)(qrow + 8);
        score_rel_g(q0, q1, kA0, colsrc, rp[wid], rp[wid + 1],
                    muL[0 * 4 + h] * 0.125f, sc, grp, j, m);
        const int* rp2 = rp + 2 * (N + 1);
        score_rel_g(q0, q1, kA2, colsrc + 2 * (size_t)E, rp2[wid], rp2[wid + 1],
                    muL[2 * 4 + h] * 0.125f, sc + 2 * E4, grp, j, m);
        m = fmaxf(m, __shfl_xor(m, 16));
        m = fmaxf(m, __shfl_xor(m, 32));
        if (grp == 0 && (j & 3) == 0) mx_e[(size_t)wid * 4 + h] = m;
    } else {
        const _Float16* qrow = &qs[(size_t)wid * 256 + j * 16];
        const f16x8 q0 = *(const f16x8*)qrow;
        const f16x8 q1 = *(const f16x8*)(qrow + 8);
        const int* rp1 = rp + (N + 1);
        score_rel_g(q0, q1, kA1, colsrc + (size_t)E, rp1[wid], rp1[wid + 1],
                    muL[1 * 4 + h] * 0.125f, sc + E4, grp, j, m);
        m = fmaxf(m, __shfl_xor(m, 16));
        m = fmaxf(m, __shfl_xor(m, 32));
        if (grp == 0 && (j & 3) == 0) mx_s[(size_t)wid * 4 + h] = m;
    }
}

// ---------------------------------------------------------------------------
// Aggregation (R12 exact form: single-pass online, __expf, NO unroll —
// R14's unroll raised VGPR 32->40 and cost 11.5us/dispatch).
// ---------------------------------------------------------------------------
__device__ __forceinline__ void agg_rel_on(
    const float* __restrict__ sc, const _Float16* __restrict__ vM,
    const int* __restrict__ cs, int beg, int end, float mh, int grp, int j,
    int h, float* accf, float& den) {
    for (int i = beg + grp; i < end; i += 4) {
        const int s = cs[i];
        const float w = __expf(sc[(size_t)i * 4 + h] - mh);
        den += w;
        const _Float16* row = &vM[(size_t)s * 256 + j * 16];
        const f16x8 v0 = *(const f16x8*)row;
        const f16x8 v1 = *(const f16x8*)(row + 8);
#pragma unroll
        for (int t = 0; t < 8; ++t) accf[t] += w * (float)v0[t];
#pragma unroll
        for (int t = 0; t < 8; ++t) accf[8 + t] += w * (float)v1[t];
    }
}

__global__ __launch_bounds__(256) void agg3_k(
    const float* __restrict__ sc, const _Float16* __restrict__ vM0,
    const _Float16* __restrict__ vM1, const _Float16* __restrict__ vM2,
    const int* __restrict__ rp, const int* __restrict__ colsrc,
    const float* __restrict__ mx_e, const float* __restrict__ mx_s,
    _Float16* __restrict__ outE, _Float16* __restrict__ outS, int N, int E) {
    const int wid = (blockIdx.x * blockDim.x + threadIdx.x) >> 6;
    if (wid >= N) return;
    const int lane = threadIdx.x & 63;
    const int grp = lane >> 4, j = lane & 15, h = j >> 2;
    const size_t E4 = (size_t)E * 4;
    float accf[16] = {};
    float den = 0.f;
    _Float16* outp;
    if (blockIdx.y == 0) {
        const float mh = mx_e[(size_t)wid * 4 + h];
        const int b0 = rp[wid], e0 = rp[wid + 1];
        const int* rp2 = rp + 2 * (N + 1);
        const int b2 = rp2[wid], e2 = rp2[wid + 1];
        agg_rel_on(sc, vM0, colsrc, b0, e0, mh, grp, j, h, accf, den);
        agg_rel_on(sc + 2 * E4, vM2, colsrc + 2 * (size_t)E, b2, e2, mh, grp,
                   j, h, accf, den);
        outp = outE;
    } else {
        const float mh = mx_s[(size_t)wid * 4 + h];
        const int* rp1 = rp + (N + 1);
        const int b1 = rp1[wid], e1 = rp1[wid + 1];
        agg_rel_on(sc + E4, vM1, colsrc + (size_t)E, b1, e1, mh, grp, j, h,
                   accf, den);
        outp = outS;
    }
    den += __shfl_xor(den, 16);
    den += __shfl_xor(den, 32);
#pragma unroll
    for (int t = 0; t < 16; ++t) {
        accf[t] += __shfl_xor(accf[t], 16);
        accf[t] += __shfl_xor(accf[t], 32);
    }
    const float dinv = 1.0f / (den + 1e-16f);
    f16x4 o;
#pragma unroll
    for (int t = 0; t < 4; ++t)
        o[t] = (_Float16)gelu_f(accf[grp * 4 + t] * dinv);
    *(f16x4*)&outp[(size_t)wid * 256 + j * 16 + grp * 4] = o;
}

// ---------------------------------------------------------------------------
// Batched head epilogue.
// ---------------------------------------------------------------------------
__global__ __launch_bounds__(256) void head2_k(const _Float16* __restrict__ t,
                                               const float* __restrict__ Wt2,
                                               const float* __restrict__ bt2,
                                               float* __restrict__ out, int M) {
    const int k = blockIdx.y;
    __shared__ float Ws[128 * 8];
    __shared__ float bs[8];
    const int tid = threadIdx.x;
    const float* W2 = Wt2 + (size_t)k * 1024;
    for (int i = tid; i < 1024; i += 256) Ws[i] = W2[i];
    if (tid < 8) bs[tid] = bt2[k * 8 + tid];
    __syncthreads();
    const int OFFA[7] = {0, 3, 6, 9, 14, 15, 16};
    const int DIMSA[7] = {3, 3, 3, 5, 1, 1, 8};
    const int nl = tid >> 3, o = tid & 7;
    const int n = blockIdx.x * 32 + nl;
    if (n >= M) return;
    const _Float16* tr = &t[(size_t)n * 896 + k * 128];
    float acc = bs[o];
#pragma unroll 8
    for (int d = 0; d < 128; ++d) acc += (float)tr[d] * Ws[d * 8 + o];
    if (o < DIMSA[k]) out[(size_t)n * 24 + OFFA[k] + o] = acc;
}

// ---------------------------------------------------------------------------

extern "C" void kernel_launch(void* const* d_in, const int* in_sizes, int n_in,
                              void* d_out, int out_size, void* d_ws,
                              size_t ws_size, hipStream_t stream) {
    const float* xe_in = (const float*)d_in[0];
    const float* xs_in = (const float*)d_in[1];
    const int* ee_src = (const int*)d_in[2];
    const int* ee_dst = (const int*)d_in[3];
    const int* es_src = (const int*)d_in[4];
    const int* es_dst = (const int*)d_in[5];
    const int* se_src = (const int*)d_in[6];
    const int* se_dst = (const int*)d_in[7];
    const float* Wk = (const float*)d_in[8];
    const float* Wq = (const float*)d_in[9];
    const float* Wv = (const float*)d_in[10];
    const float* Wa = (const float*)d_in[11];
    const float* skip = (const float*)d_in[12];
    const float* Arel = (const float*)d_in[13];
    const float* Mrel = (const float*)d_in[14];
    const float* mu = (const float*)d_in[15];
    const float* Wsh = (const float*)d_in[16];
    const float* bsh = (const float*)d_in[17];
    const float* Wt1 = (const float*)d_in[18];
    const float* bt1 = (const float*)d_in[19];
    const float* Wt2 = (const float*)d_in[20];
    const float* bt2 = (const float*)d_in[21];
    float* out = (float*)d_out;

    const int N = in_sizes[0] / CDIM;  // 50000
    const int E = in_sizes[2];         // 200000
    const size_t NC = (size_t)N * CDIM;
    const size_t E4 = (size_t)E * 4;
    const size_t N4 = (size_t)N * 4;
    const int PB = (N + 255) / 256;

    const size_t halfs = 7 * NC + 32 * (size_t)AR_R + 7 * 32768;
    const size_t floats = 3 * E4 + 2 * N4;
    const size_t ints =
        3 * (size_t)(N + 1) + 3 * (size_t)E + 3 * (size_t)N + 3 * (size_t)PB;
    const size_t need = halfs * 2 + floats * 4 + ints * 4;
    if (ws_size < need) return;

    _Float16* xeH = (_Float16*)d_ws;
    _Float16* xsH = xeH + NC;
    _Float16* Hb = xsH + NC;
    _Float16* H1 = Hb;
    _Float16* H2 = Hb + NC;
    _Float16* H3 = Hb + 2 * NC;
    _Float16* H4 = Hb + 3 * NC;
    _Float16* H5 = Hb + 4 * NC;
    _Float16* arena = Hb + 5 * NC;
    _Float16* SA = arena + (size_t)30 * AR_R;
    _Float16* HA = SA + (size_t)2 * AR_R;
    float* sc = (float*)(HA + (size_t)7 * 32768);
    float* mx_e = sc + 3 * E4;
    float* mx_s = mx_e + N4;
    int* rp = (int*)(mx_s + N4);
    int* colsrc = rp + 3 * (size_t)(N + 1);
    int* cnt = colsrc + 3 * (size_t)E;
    int* partials = cnt + 3 * (size_t)N;

    const int gx = (N + 127) / 128;
    const dim3 e3((E + 255) / 256, 3);
    const dim3 p3(PB, 3);
    const int wave_blocks = (N + 3) / 4;
    const int zc_blocks = (3 * N + 255) / 256;

    // ---- CSR build ----
    zero_k<<<zc_blocks, 256, 0, stream>>>(cnt, 3 * (size_t)N);
    hist3_k<<<e3, 256, 0, stream>>>(ee_dst, es_dst, se_dst, cnt, N, E);
    partial_k<<<p3, 256, 0, stream>>>(cnt, partials, N, PB);
    scanp_k<<<dim3(1, 3), 256, 0, stream>>>(partials, rp, N, PB, E);
    rpwrite_k<<<p3, 256, 0, stream>>>(cnt, partials, rp, N, PB);
    zero_k<<<zc_blocks, 256, 0, stream>>>(cnt, 3 * (size_t)N);
    scatter3_k<<<e3, 256, 0, stream>>>(ee_dst, es_dst, se_dst, ee_src, es_src,
                                       se_src, rp, cnt, colsrc, N, E);

    // ---- weight prep ----
    prep_layer_k<<<dim3(256, 30), 256, 0, stream>>>(Wk, Wq, Wv, Wa, Arel, Mrel,
                                                    arena);
    prep_stack_k<<<dim3(256, 2), 256, 0, stream>>>(Wsh, SA);
    prep_heads_k<<<dim3(128, 7), 256, 0, stream>>>(Wt1, HA);

    // ---- initial fp16 activations ----
    cvt2_k<<<dim3(1024, 2), 256, 0, stream>>>(xe_in, xs_in, xeH, xsH, NC / 4);

    for (int l = 0; l < 3; ++l) {
        _Float16* L = arena + (size_t)l * 10 * AR_R;
        projq_k<<<dim3(10, gx), 256, 0, stream>>>(xeH, xsH, L, Hb, N);
        score3_k<<<dim3(wave_blocks, 2), 256, 0, stream>>>(
            H1, H2, H3, H4, H5, rp, colsrc, mu + l * 12, sc, mx_e, mx_s, N, E);
        projv_k<<<dim3(6, gx), 256, 0, stream>>>(xeH, xsH, L, Hb, N);
        agg3_k<<<dim3(wave_blocks, 2), 256, 0, stream>>>(
            sc, H2, H3, H5, rp, colsrc, mx_e, mx_s, H1, H4, N, E);
        update2_k<<<dim3(4, gx), 256, 0, stream>>>(
            H1, H4, L + 8 * AR_R, L + 9 * AR_R, xeH, xsH, skip + l * 2, N);
    }

    // shared linear stack
    gemm_h<2, false><<<dim3(2, gx), 256, 0, stream>>>(xeH, SA, H5, N, 256, 0,
                                                      bsh, nullptr);
    gemm_h<2, false><<<dim3(2, gx), 256, 0, stream>>>(H5, SA + AR_R, xsH, N,
                                                      256, 0, bsh + 256, nullptr);
    // 7 task heads
    gemm_h<2, false><<<dim3(7, gx), 256, 0, stream>>>(xsH, HA, Hb, N, 896, 0,
                                                      bt1, nullptr);
    head2_k<<<dim3((N + 31) / 32, 7), 256, 0, stream>>>(Hb, Wt2, bt2, out, N);
}